// Round 11
// baseline (480.832 us; speedup 1.0000x reference)
//
#include <hip/hip_runtime.h>
#include <hip/hip_bf16.h>

// ---------------------------------------------------------------------------
// Transformer encoder layer (post-norm), bf16 MFMA implementation.
// D=1024, H=16, HD=64, FF=4096, B=4, S=2048 -> 8192 tokens.
//
// Round 17 (= round 16 + coalesced V-transpose store + slimmer prep):
//  - MODE 4 V-blocks (n0>=2048, block-uniform): the 128x128 V-tile is
//    staged TRANSPOSED into LDS (reusing the 32KB As/Bs region after a
//    fence barrier), then written to Vt as ushort8 runs -> 256B contiguous
//    segments instead of per-lane 8B at 4KB stride (32x coalescing on
//    16MB of V writes). LDS size unchanged (32768) -> occupancy stays 5.
//  - prep_kernel: 64x64 transpose tiles + 8-elem cast -> 7168 blocks
//    (was 20480).
//  - everything else byte-identical to the verified 461us round-16 config
//    (quad-Q attention, m97 128x128 GEMMs, MODE 7 Wout, MODE 9 FFN2,
//    bf16 LNs, fused prep).
// ---------------------------------------------------------------------------

typedef __attribute__((ext_vector_type(8))) short          short8;
typedef __attribute__((ext_vector_type(8))) unsigned short ushort8;
typedef __attribute__((ext_vector_type(4))) float          f32x4;
typedef __attribute__((ext_vector_type(2))) unsigned int   uivec2;

__device__ __forceinline__ unsigned short f2bf(float f) {
    union { float f; unsigned int u; } v; v.f = f;
    unsigned int u = v.u;
    unsigned int r = (u + 0x7fffu + ((u >> 16) & 1u)) >> 16;
    return (unsigned short)r;
}

__device__ __forceinline__ float bf2f(unsigned short u) {
    union { unsigned int u; float f; } v; v.u = ((unsigned int)u) << 16;
    return v.f;
}

// truncate-pack two f32 -> (bf16(hi)<<16)|bf16(lo)
__device__ __forceinline__ unsigned int pack_bf16_trunc(float lo, float hi) {
    union { float f; unsigned int u; } a, b; a.f = lo; b.f = hi;
    return __builtin_amdgcn_perm(b.u, a.u, 0x07060302u);  // {b.hi16, a.hi16}
}

// async global->LDS, 16 B per lane. LDS dest = wave-uniform base + lane*16.
__device__ __forceinline__ void async_load16(const void* g, void* l) {
    __builtin_amdgcn_global_load_lds(
        (const __attribute__((address_space(1))) void*)(unsigned long long)g,
        (__attribute__((address_space(3))) void*)(unsigned long long)l,
        16, 0, 0);
}

// exp2 of 16 scores (4x f32x4) -> two bf16x8 PV A-fragments, via
// permlane32_swap + permlane16_swap (round-7 verified mapping).
__device__ __forceinline__ void softmax_frag(const f32x4* s,
                                             short8& pf0, short8& pf1) {
    unsigned int aw[4], bw[4];
#pragma unroll
    for (int nt = 0; nt < 4; nt++) {
        float p0 = __builtin_amdgcn_exp2f(s[nt][0]);
        float p1 = __builtin_amdgcn_exp2f(s[nt][1]);
        float p2 = __builtin_amdgcn_exp2f(s[nt][2]);
        float p3 = __builtin_amdgcn_exp2f(s[nt][3]);
        aw[nt] = pack_bf16_trunc(p0, p1);
        bw[nt] = pack_bf16_trunc(p2, p3);
    }
    uivec2 rA = __builtin_amdgcn_permlane32_swap(aw[0], aw[1], false, false);
    uivec2 sA = __builtin_amdgcn_permlane32_swap(aw[2], aw[3], false, false);
    uivec2 rB = __builtin_amdgcn_permlane32_swap(bw[0], bw[1], false, false);
    uivec2 sB = __builtin_amdgcn_permlane32_swap(bw[2], bw[3], false, false);
    uivec2 tA = __builtin_amdgcn_permlane16_swap(rA.x, rA.y, false, false);
    uivec2 uA = __builtin_amdgcn_permlane16_swap(sA.x, sA.y, false, false);
    uivec2 tB = __builtin_amdgcn_permlane16_swap(rB.x, rB.y, false, false);
    uivec2 uB = __builtin_amdgcn_permlane16_swap(sB.x, sB.y, false, false);
    union { unsigned int w[4]; short8 v; } P0, P1;
    P0.w[0] = tA.x; P0.w[1] = tB.x; P0.w[2] = tA.y; P0.w[3] = tB.y;
    P1.w[0] = uA.x; P1.w[1] = uB.x; P1.w[2] = uA.y; P1.w[3] = uB.y;
    pf0 = P0.v;
    pf1 = P1.v;
}

// ---------------------------------------------------------------------------
// Fused prep: cast src -> src_bf (8 elems/thread), and 4 weight transposes
// with 64x64 tiles (W[K,N] f32 -> Wt[N,K] bf16). Region dispatch:
//   [0, 4096)       cast
//   [4096, 4864)    Wqkv  (48 x 16)
//   [4864, 5120)    Wout  (16 x 16)
//   [5120, 6144)    W1    (64 x 16)
//   [6144, 7168)    W2    (16 x 64)
__device__ __forceinline__ void transpose_tile64(
    const float* __restrict__ W, unsigned short* __restrict__ Wt,
    int K, int N, int n0, int k0, float (*tile)[65]) {
    int tx = threadIdx.x & 63, ty = threadIdx.x >> 6;
#pragma unroll
    for (int i = 0; i < 64; i += 4)
        tile[ty + i][tx] = W[(size_t)(k0 + ty + i) * N + n0 + tx];
    __syncthreads();
#pragma unroll
    for (int i = 0; i < 64; i += 4)
        Wt[(size_t)(n0 + ty + i) * K + k0 + tx] = f2bf(tile[tx][ty + i]);
}

__global__ __launch_bounds__(256) void prep_kernel(
    const float* __restrict__ src, unsigned short* __restrict__ src_bf,
    const float* __restrict__ Wqkv, unsigned short* __restrict__ Wqkv_t,
    const float* __restrict__ Wout, unsigned short* __restrict__ Wout_t,
    const float* __restrict__ W1, unsigned short* __restrict__ W1_t,
    const float* __restrict__ W2, unsigned short* __restrict__ W2_t) {
    __shared__ float tile[64][65];
    const int bid = blockIdx.x;
    if (bid < 4096) {
        size_t i = ((size_t)bid * 256 + threadIdx.x) * 8;
        float4 v0 = *(const float4*)(src + i);
        float4 v1 = *(const float4*)(src + i + 4);
        ushort8 o;
        o[0] = f2bf(v0.x); o[1] = f2bf(v0.y); o[2] = f2bf(v0.z); o[3] = f2bf(v0.w);
        o[4] = f2bf(v1.x); o[5] = f2bf(v1.y); o[6] = f2bf(v1.z); o[7] = f2bf(v1.w);
        *(ushort8*)(src_bf + i) = o;
    } else if (bid < 4864) {
        int r = bid - 4096;
        transpose_tile64(Wqkv, Wqkv_t, 1024, 3072, (r % 48) * 64, (r / 48) * 64, tile);
    } else if (bid < 5120) {
        int r = bid - 4864;
        transpose_tile64(Wout, Wout_t, 1024, 1024, (r % 16) * 64, (r / 16) * 64, tile);
    } else if (bid < 6144) {
        int r = bid - 5120;
        transpose_tile64(W1, W1_t, 1024, 4096, (r % 64) * 64, (r / 64) * 64, tile);
    } else {
        int r = bid - 6144;
        transpose_tile64(W2, W2_t, 4096, 1024, (r % 16) * 64, (r / 16) * 64, tile);
    }
}

// ---------------------------------------------------------------------------
// 128x128 GEMM (m97 structure), BK=32, 256 thr (4 waves 2x2), 16x16x32 MFMA.
// Double-buffered LDS, one barrier per K-iter, global_load_lds(16B) staging,
// fetch-side XOR chunk swizzle (phys chunk p holds logical p^(row&3)).
// MODE 0: bf16 out; 1: outF = acc + resF; 2: outB = bf16(relu(acc+bias));
// MODE 4: qkv: col<1024 -> bf16(v*log2e/8); 1024..2047 -> bf16; >=2048 ->
//         vtB^T via LDS transpose (coalesced ushort8 stores).
// MODE 7: outB = bf16(acc + float(resB))           (Wout, bf16 x1)
// MODE 9: outB = bf16(acc + bias + float(resB))    (FFN2 fused, bf16 x2)
template <int MODE>
__global__ __launch_bounds__(256) void gemm_bf16_kernel(
    const unsigned short* __restrict__ A, const unsigned short* __restrict__ Bt,
    int M, int N, int K, int Kstride,
    float* __restrict__ outF, unsigned short* __restrict__ outB,
    const float* __restrict__ bias,
    const float* __restrict__ resF, const unsigned short* __restrict__ resB,
    unsigned short* __restrict__ vtB) {
    __shared__ unsigned short Sh[4][128 * 32];   // As = Sh[0..1], Bs = Sh[2..3]
    unsigned short (*As)[128 * 32] = &Sh[0];
    unsigned short (*Bs)[128 * 32] = &Sh[2];

    const int t = threadIdx.x;
    const int m0 = blockIdx.x * 128, n0 = blockIdx.y * 128;
    const int koff = blockIdx.z * K;
    const int wid = t >> 6, lane = t & 63;
    const int wm = wid >> 1, wn = wid & 1;
    const int lr = lane & 15, quad = lane >> 4;

    const int srow = lane >> 2;                       // 0..15
    const int sch  = ((lane & 3) ^ (srow & 3)) * 8;   // swizzled logical chunk
    const unsigned short* Ag =
        A  + (size_t)(m0 + wid * 32 + srow) * Kstride + koff + sch;
    const unsigned short* Bg =
        Bt + (size_t)(n0 + wid * 32 + srow) * Kstride + koff + sch;
    const int wofs = (wid * 32) * 32;
    const size_t rstep = (size_t)16 * Kstride;

    const int axs = ((quad ^ (lr & 3))) * 8;          // phys chunk for reads
    f32x4 acc[4][4] = {};

    const int nK = K >> 5;
    // initial stage into buf 0
    async_load16(Ag,         &As[0][wofs]);
    async_load16(Ag + rstep, &As[0][wofs + 16 * 32]);
    async_load16(Bg,         &Bs[0][wofs]);
    async_load16(Bg + rstep, &Bs[0][wofs + 16 * 32]);

    for (int kt = 0; kt < nK; kt++) {
        const int cur = kt & 1, nxt = cur ^ 1;
        __syncthreads();   // drains own DMA (vmcnt) + prior LDS reads
        if (kt + 1 < nK) {
            const int k1 = (kt + 1) * 32;
            async_load16(Ag + k1,         &As[nxt][wofs]);
            async_load16(Ag + k1 + rstep, &As[nxt][wofs + 16 * 32]);
            async_load16(Bg + k1,         &Bs[nxt][wofs]);
            async_load16(Bg + k1 + rstep, &Bs[nxt][wofs + 16 * 32]);
        }

        short8 af[4], bfr[4];
#pragma unroll
        for (int i = 0; i < 4; i++) {
            af[i]  = *(const short8*)&As[cur][(wm * 64 + i * 16 + lr) * 32 + axs];
            bfr[i] = *(const short8*)&Bs[cur][(wn * 64 + i * 16 + lr) * 32 + axs];
        }
#pragma unroll
        for (int mi = 0; mi < 4; mi++)
#pragma unroll
            for (int ni = 0; ni < 4; ni++)
                acc[mi][ni] = __builtin_amdgcn_mfma_f32_16x16x32_bf16(
                    af[mi], bfr[ni], acc[mi][ni], 0, 0, 0);
    }

    const float QSC = 0.18033688011112042f;  // (1/8) * log2(e)

    if (MODE == 4 && n0 >= 2048) {
        // V-block: stage transposed tile T[c][s] (stride 128 shorts) in the
        // As/Bs region (exactly 32KB), then coalesced ushort8 stores.
        unsigned short* T = &Sh[0][0];
        __syncthreads();   // fence: other waves' last K-loop LDS reads done
#pragma unroll
        for (int mi = 0; mi < 4; mi++)
#pragma unroll
            for (int ni = 0; ni < 4; ni++) {
                const int cl = wn * 64 + ni * 16 + lr;
                const int s0 = wm * 64 + mi * 16 + quad * 4;
                ushort4 ov;
                ov.x = f2bf(acc[mi][ni][0]); ov.y = f2bf(acc[mi][ni][1]);
                ov.z = f2bf(acc[mi][ni][2]); ov.w = f2bf(acc[mi][ni][3]);
                *(ushort4*)&T[cl * 128 + s0] = ov;
            }
        __syncthreads();
        const int bb = m0 >> 11, ss0 = m0 & 2047;
        const int li = t & 15;
#pragma unroll
        for (int pass = 0; pass < 8; pass++) {
            const int cl = (t >> 4) + pass * 16;
            ushort8 vv = *(const ushort8*)&T[cl * 128 + li * 8];
            *(ushort8*)&vtB[((size_t)bb * 1024 + (n0 - 2048 + cl)) * 2048 +
                            ss0 + li * 8] = vv;
        }
        return;
    }

#pragma unroll
    for (int mi = 0; mi < 4; mi++)
#pragma unroll
        for (int ni = 0; ni < 4; ni++) {
            const int col  = n0 + wn * 64 + ni * 16 + lr;
            const int row0 = m0 + wm * 64 + mi * 16 + quad * 4;
#pragma unroll
            for (int r = 0; r < 4; r++) {
                size_t idx = (size_t)(row0 + r) * N + col;
                float v = acc[mi][ni][r];
                if (MODE == 4) {
                    outB[idx] = f2bf(col < 1024 ? v * QSC : v);
                } else if (MODE == 0) {
                    outB[idx] = f2bf(v);
                } else if (MODE == 1) {
                    outF[idx] = v + resF[idx];
                } else if (MODE == 2) {
                    v += bias[col];
                    outB[idx] = f2bf(v > 0.f ? v : 0.f);
                } else if (MODE == 7) {
                    outB[idx] = f2bf(v + bf2f(resB[idx]));
                } else if (MODE == 9) {
                    outB[idx] = f2bf(v + bias[col] + bf2f(resB[idx]));
                }
            }
        }
}

// ---------------------------------------------------------------------------
// Flash attention, S^T formulation, no online max (scores bounded).
// qkv bf16: [(b*2048+s)*3072 + comp*1024 + h*64 + hd]; Q pre-scaled by
// log2e/8, so p = exp2(mfma output). Vt bf16: [(b*1024+h*64+hd)*2048+s].
// QUAD-Q: QBLK=256, 4 waves, each wave owns 64 queries as four 16-row
// fragments. K/V LDS fragments read once per wave per kt feed all four.
__global__ __launch_bounds__(256, 2) void attention_kernel(
    const unsigned short* __restrict__ qkv, const unsigned short* __restrict__ Vt,
    unsigned short* __restrict__ ctx) {
    __shared__ unsigned short Kbuf[2][64 * 64];   // [key][hd], chunk-swizzled
    __shared__ unsigned short Vbuf[2][64 * 64];   // [hd][key], chunk-swizzled

    const int qt = blockIdx.x, h = blockIdx.y, b = blockIdx.z;
    const int t = threadIdx.x, wid = t >> 6, lane = t & 63;
    const int lr = lane & 15, quad = lane >> 4;
    const int q0 = qt * 256 + wid * 64;

    short8 qf[4][2];
#pragma unroll
    for (int f = 0; f < 4; f++) {
        size_t qb = ((size_t)(b * 2048 + q0 + f * 16 + lr)) * 3072 + h * 64;
        qf[f][0] = *(const short8*)(qkv + qb + quad * 8);
        qf[f][1] = *(const short8*)(qkv + qb + 32 + quad * 8);
    }

    const int srow = wid * 8 + (lane >> 3);            // 0..31
    const int sch  = ((lane & 7) ^ (srow & 7)) * 8;    // fetch-side swizzle
    const unsigned short* Kg =
        qkv + (size_t)b * 2048 * 3072 + 1024 + h * 64 + (size_t)srow * 3072 + sch;
    const unsigned short* Vg =
        Vt + ((size_t)b * 1024 + h * 64 + srow) * 2048 + sch;
    unsigned short* KsB = (unsigned short*)&Kbuf[0][(wid * 8) * 64];
    unsigned short* VsB = (unsigned short*)&Vbuf[0][(wid * 8) * 64];
    const int bufstep = 64 * 64;

    short8 ones;
#pragma unroll
    for (int i = 0; i < 8; i++) ones[i] = (short)0x3F80;  // bf16 1.0

    f32x4 o[4][4] = {};
    f32x4 lacc[4] = {};

#pragma unroll
    for (int half = 0; half < 2; half++) {
        async_load16(Kg + (size_t)(half * 32) * 3072, KsB + half * 32 * 64);
        async_load16(Vg + (size_t)(half * 32) * 2048, VsB + half * 32 * 64);
    }

    const int swz = lr & 7;

    for (int kt = 0; kt < 32; kt++) {
        const int cur = kt & 1, nxt = cur ^ 1;
        __syncthreads();
        if (kt + 1 < 32) {
#pragma unroll
            for (int half = 0; half < 2; half++) {
                async_load16(Kg + (size_t)((kt + 1) * 64 + half * 32) * 3072,
                             KsB + nxt * bufstep + half * 32 * 64);
                async_load16(Vg + (size_t)(half * 32) * 2048 + (kt + 1) * 64,
                             VsB + nxt * bufstep + half * 32 * 64);
            }
        }

        const unsigned short* Kc = &Kbuf[cur][0];
        const unsigned short* Vc = &Vbuf[cur][0];

        f32x4 s[4][4] = {};
#pragma unroll
        for (int nt = 0; nt < 4; nt++) {
            const unsigned short* krow = Kc + (nt * 16 + lr) * 64;
            short8 kf0 = *(const short8*)(krow + (quad ^ swz) * 8);
            short8 kf1 = *(const short8*)(krow + ((quad + 4) ^ swz) * 8);
#pragma unroll
            for (int f = 0; f < 4; f++) {
                s[f][nt] = __builtin_amdgcn_mfma_f32_16x16x32_bf16(
                    kf0, qf[f][0], s[f][nt], 0, 0, 0);
                s[f][nt] = __builtin_amdgcn_mfma_f32_16x16x32_bf16(
                    kf1, qf[f][1], s[f][nt], 0, 0, 0);
            }
        }

        short8 pf[4][2];
#pragma unroll
        for (int f = 0; f < 4; f++)
            softmax_frag(s[f], pf[f][0], pf[f][1]);

#pragma unroll
        for (int nt = 0; nt < 4; nt++) {
            const unsigned short* vrow = Vc + (nt * 16 + lr) * 64;
            short8 vf0 = *(const short8*)(vrow + (quad ^ swz) * 8);
            short8 vf1 = *(const short8*)(vrow + ((quad + 4) ^ swz) * 8);
#pragma unroll
            for (int f = 0; f < 4; f++) {
                o[f][nt] = __builtin_amdgcn_mfma_f32_16x16x32_bf16(
                    pf[f][0], vf0, o[f][nt], 0, 0, 0);
                o[f][nt] = __builtin_amdgcn_mfma_f32_16x16x32_bf16(
                    pf[f][1], vf1, o[f][nt], 0, 0, 0);
            }
        }
#pragma unroll
        for (int f = 0; f < 4; f++) {
            lacc[f] = __builtin_amdgcn_mfma_f32_16x16x32_bf16(
                pf[f][0], ones, lacc[f], 0, 0, 0);
            lacc[f] = __builtin_amdgcn_mfma_f32_16x16x32_bf16(
                pf[f][1], ones, lacc[f], 0, 0, 0);
        }
    }

#pragma unroll
    for (int f = 0; f < 4; f++)
#pragma unroll
        for (int r = 0; r < 4; r++) {
            float li = 1.f / lacc[f][r];
            int q = q0 + f * 16 + quad * 4 + r;
#pragma unroll
            for (int nt = 0; nt < 4; nt++)
                ctx[((size_t)(b * 2048 + q)) * 1024 + h * 64 + nt * 16 + lr] =
                    f2bf(o[f][nt][r] * li);
        }
}

// ---------------------------------------------------------------------------
// LayerNorm over rows of 1024, bf16 input. OUTMODE 0: f32 out; 1: bf16 out.
template <int OUTMODE>
__global__ __launch_bounds__(256) void layernorm_bf_kernel(
    const unsigned short* __restrict__ x, const float* __restrict__ g,
    const float* __restrict__ be, float* __restrict__ yF,
    unsigned short* __restrict__ yB) {
    const int row = blockIdx.x, t = threadIdx.x;
    ushort4 xb = *(const ushort4*)(x + (size_t)row * 1024 + t * 4);
    float4 v;
    v.x = bf2f(xb.x); v.y = bf2f(xb.y); v.z = bf2f(xb.z); v.w = bf2f(xb.w);
    float s  = v.x + v.y + v.z + v.w;
    float sq = v.x * v.x + v.y * v.y + v.z * v.z + v.w * v.w;
#pragma unroll
    for (int d = 1; d < 64; d <<= 1) {
        s  += __shfl_xor(s, d, 64);
        sq += __shfl_xor(sq, d, 64);
    }
    __shared__ float sh[8];
    int wid = t >> 6, lane = t & 63;
    if (lane == 0) { sh[wid] = s; sh[4 + wid] = sq; }
    __syncthreads();
    s  = sh[0] + sh[1] + sh[2] + sh[3];
    sq = sh[4] + sh[5] + sh[6] + sh[7];
    float mu  = s * (1.f / 1024.f);
    float var = sq * (1.f / 1024.f) - mu * mu;
    float rstd = rsqrtf(var + 1e-5f);
    float4 gv = *(const float4*)(g + t * 4);
    float4 bv = *(const float4*)(be + t * 4);
    float4 y;
    y.x = (v.x - mu) * rstd * gv.x + bv.x;
    y.y = (v.y - mu) * rstd * gv.y + bv.y;
    y.z = (v.z - mu) * rstd * gv.z + bv.z;
    y.w = (v.w - mu) * rstd * gv.w + bv.w;
    if (OUTMODE == 0) {
        *(float4*)(yF + (size_t)row * 1024 + t * 4) = y;
    } else {
        ushort4 o;
        o.x = f2bf(y.x); o.y = f2bf(y.y); o.z = f2bf(y.z); o.w = f2bf(y.w);
        *(ushort4*)(yB + (size_t)row * 1024 + t * 4) = o;
    }
}

// ---------------------------------------------------------------------------
extern "C" void kernel_launch(void* const* d_in, const int* in_sizes, int n_in,
                              void* d_out, int out_size, void* d_ws, size_t ws_size,
                              hipStream_t stream) {
    const float* src  = (const float*)d_in[0];
    const float* Wqkv = (const float*)d_in[1];
    const float* Wout = (const float*)d_in[2];
    const float* W1   = (const float*)d_in[3];
    const float* b1   = (const float*)d_in[4];
    const float* W2   = (const float*)d_in[5];
    const float* b2   = (const float*)d_in[6];
    const float* g1   = (const float*)d_in[7];
    const float* be1  = (const float*)d_in[8];
    const float* g2   = (const float*)d_in[9];
    const float* be2  = (const float*)d_in[10];
    float* out = (float*)d_out;

    const size_t NT = 8192;  // tokens = 4*2048
    char* ws = (char*)d_ws;
    unsigned short* src_bf = (unsigned short*)ws; ws += NT * 1024 * 2;
    unsigned short* Wqkv_t = (unsigned short*)ws; ws += (size_t)3072 * 1024 * 2;
    unsigned short* Wout_t = (unsigned short*)ws; ws += (size_t)1024 * 1024 * 2;
    unsigned short* W1_t   = (unsigned short*)ws; ws += (size_t)4096 * 1024 * 2;
    unsigned short* W2_t   = (unsigned short*)ws; ws += (size_t)1024 * 4096 * 2;
    unsigned short* qkv_bf = (unsigned short*)ws; ws += NT * 3072 * 2;  // 48 MB
    unsigned short* ctx_bf = (unsigned short*)ws; ws += NT * 1024 * 2;  // 16 MB
    unsigned short* x1_bf  = (unsigned short*)ws; ws += NT * 1024 * 2;  // 16 MB
    unsigned short* y1_bf  = (unsigned short*)ws; ws += NT * 1024 * 2;
    unsigned short* h_bf   = (unsigned short*)ws; ws += NT * 4096 * 2;
    // aliases over dead buffers:
    unsigned short* Vt = h_bf;      // Vt dead before GEMM3 writes h_bf
    unsigned short* x2_bf = qkv_bf; // qkv dead after attention

    // fused prep: cast + 4 transposes, one launch
    prep_kernel<<<7168, 256, 0, stream>>>(
        src, src_bf, Wqkv, Wqkv_t, Wout, Wout_t, W1, W1_t, W2, W2_t);

    // qkv = src @ Wqkv  (Q scaled -> qkv_bf; K -> qkv_bf; V -> Vt transposed)
    gemm_bf16_kernel<4><<<dim3(64, 24), 256, 0, stream>>>(
        src_bf, Wqkv_t, 8192, 3072, 1024, 1024,
        nullptr, qkv_bf, nullptr, nullptr, nullptr, Vt);
    // attention (quad-Q: QBLK=256)
    attention_kernel<<<dim3(8, 16, 4), 256, 0, stream>>>(qkv_bf, Vt, ctx_bf);
    // x1 = bf16(ctx @ Wout + src_bf)   (MODE 7)
    gemm_bf16_kernel<7><<<dim3(64, 8), 256, 0, stream>>>(
        ctx_bf, Wout_t, 8192, 1024, 1024, 1024,
        nullptr, x1_bf, nullptr, nullptr, src_bf, nullptr);
    // y1 = LN1(x1)  (bf16 in, bf16 out)
    layernorm_bf_kernel<1><<<8192, 256, 0, stream>>>(
        x1_bf, g1, be1, nullptr, y1_bf);
    // h = relu(y1 @ W1 + b1)
    gemm_bf16_kernel<2><<<dim3(64, 32), 256, 0, stream>>>(
        y1_bf, W1_t, 8192, 4096, 1024, 1024,
        nullptr, h_bf, b1, nullptr, nullptr, nullptr);
    // x2 = bf16(h @ W2 + b2 + y1)   (MODE 9, unsplit K=4096)
    gemm_bf16_kernel<9><<<dim3(64, 8), 256, 0, stream>>>(
        h_bf, W2_t, 8192, 1024, 4096, 4096,
        nullptr, x2_bf, b2, nullptr, y1_bf, nullptr);
    // out = LN2(x2)  (bf16 in, f32 out)
    layernorm_bf_kernel<0><<<8192, 256, 0, stream>>>(
        x2_bf, g2, be2, out, nullptr);
}